// Round 2
// baseline (26.889 us; speedup 1.0000x reference)
//
#include <hip/hip_runtime.h>

// MedSAM3D neighborhood compression:
//   out[f,h,w] = sum_n img[f,h,w,n] * W[f,n]
// B=1, F=256, H=W=64, N=25, fp32. Memory-bound: 105 MB read + 4.2 MB write.
//
// R2 strategy: NO LDS, NO barrier. Each thread computes 4 consecutive
// outputs; its input slice is 100 contiguous floats = 25 float4 at byte base
// t*400 (16B-aligned). Pure streaming read->FMA->float4 store, like the
// 7.2 TB/s fill kernels this bench shows. Element j of the slice belongs to
// output j/25, neighbor j%25 -- all compile-time after full unroll.

constexpr int NN    = 25;
constexpr int BLOCK = 256;
constexpr int OPT   = 4;  // outputs per thread

__global__ __launch_bounds__(BLOCK) void medsam_compress_kernel(
    const float* __restrict__ img,   // [F*H*W*N]
    const float* __restrict__ W,     // [F*N]
    float* __restrict__ out)         // [F*H*W]
{
    const long long t  = (long long)blockIdx.x * BLOCK + threadIdx.x;
    const long long o0 = t * OPT;                 // first of 4 outputs
    // 4-aligned output group never crosses a channel boundary (4 | 4096).
    int f = (int)(o0 >> 12);                      // o0 / (64*64)
    f = __builtin_amdgcn_readfirstlane(f);        // wave-uniform -> s_load W

    const float* __restrict__ Wf = W + f * NN;
    float w[NN];
    #pragma unroll
    for (int n = 0; n < NN; ++n) w[n] = Wf[n];

    const float4* __restrict__ src =
        reinterpret_cast<const float4*>(img + o0 * NN);  // t*400 B, aligned

    float acc[OPT] = {0.f, 0.f, 0.f, 0.f};
    #pragma unroll
    for (int k = 0; k < NN; ++k) {
        const float4 v = src[k];
        const int j = 4 * k;                      // element index 0..99
        acc[(j + 0) / NN] += v.x * w[(j + 0) % NN];
        acc[(j + 1) / NN] += v.y * w[(j + 1) % NN];
        acc[(j + 2) / NN] += v.z * w[(j + 2) % NN];
        acc[(j + 3) / NN] += v.w * w[(j + 3) % NN];
    }

    float4 res = make_float4(acc[0], acc[1], acc[2], acc[3]);
    *reinterpret_cast<float4*>(out + o0) = res;
}

extern "C" void kernel_launch(void* const* d_in, const int* in_sizes, int n_in,
                              void* d_out, int out_size, void* d_ws, size_t ws_size,
                              hipStream_t stream) {
    const float* img = (const float*)d_in[0];  // (1,256,64,64,25) f32
    const float* W   = (const float*)d_in[1];  // (256,25) f32
    float* out       = (float*)d_out;          // (1,256,64,64) f32

    const int threads = out_size / OPT;        // 262,144
    const int grid    = threads / BLOCK;       // 1024 blocks

    medsam_compress_kernel<<<grid, BLOCK, 0, stream>>>(img, W, out);
}

// Round 3
// 21.258 us; speedup vs baseline: 1.2649x; 1.2649x over previous
//
#include <hip/hip_runtime.h>

// MedSAM3D neighborhood compression: out[f,h,w] = sum_n img[f,h,w,n]*W[f,n]
// B=1, F=256, H=W=64, N=25, fp32. Memory-bound: 105 MB read + 4.2 MB write.
//
// R3: wave-autonomous staging. Each wave owns 64 consecutive outputs
// (= 1600 contiguous input floats), staged global->LDS directly with
// __builtin_amdgcn_global_load_lds (6 x 16B-granule + 1 x 4B-granule,
// linear LDS dest = the HW's wave-uniform-base + lane*size pattern).
// NO __syncthreads, no VGPR round-trip: only a wave-scope vmcnt(0).
// Dot at LDS stride 25 (odd -> 2 lanes/bank = free), block-uniform W
// (s_load), coalesced dword store. 24 waves/CU all free-running.

constexpr int NN    = 25;
constexpr int BLOCK = 256;
constexpr int WAVES = BLOCK / 64;
constexpr int OPW   = 64;          // outputs per wave
constexpr int FPW   = OPW * NN;    // 1600 floats per wave

typedef __attribute__((address_space(3))) void       lds_void;
typedef const __attribute__((address_space(1))) void gbl_void;

__global__ __launch_bounds__(BLOCK) void medsam_compress_kernel(
    const float* __restrict__ img,   // [F*H*W*N]
    const float* __restrict__ W,     // [F*N]
    float* __restrict__ out)         // [F*H*W]
{
    __shared__ float lds[WAVES][FPW];   // 4 x 6400 B = 25,600 B

    const int tid  = threadIdx.x;
    const int w    = tid >> 6;          // wave id in block (uniform)
    const int lane = tid & 63;
    const int gw   = blockIdx.x * WAVES + w;   // global wave id

    const float* gbase = img + (long long)gw * FPW;

    // ---- stage 1600 floats: 6 x (64 lanes x 16B) + 1 x (64 lanes x 4B) ----
    #pragma unroll
    for (int k = 0; k < 6; ++k) {
        __builtin_amdgcn_global_load_lds(
            (gbl_void*)(gbase + k * 256 + lane * 4),   // per-lane global src
            (lds_void*)&lds[w][k * 256],               // wave-uniform LDS base
            16, 0, 0);
    }
    __builtin_amdgcn_global_load_lds(
        (gbl_void*)(gbase + 1536 + lane),
        (lds_void*)&lds[w][1536],
        4, 0, 0);

    // ---- weights: channel f = gw/64 (wave-uniform) -> scalar loads ----
    const int f = __builtin_amdgcn_readfirstlane(gw >> 6);
    const float* __restrict__ Wf = W + f * NN;
    float wreg[NN];
    #pragma unroll
    for (int n = 0; n < NN; ++n) wreg[n] = Wf[n];

    // ---- wave-scope wait: our 7 staging loads are the only vmcnt ops ----
    asm volatile("s_waitcnt vmcnt(0)" ::: "memory");
    __builtin_amdgcn_sched_barrier(0);

    // ---- dot: 25 ds_read_b32, lane stride 25 (odd) -> conflict-free ----
    const float* row = &lds[w][lane * NN];
    float acc = 0.f;
    #pragma unroll
    for (int n = 0; n < NN; ++n)
        acc += row[n] * wreg[n];

    out[(long long)gw * OPW + lane] = acc;
}

extern "C" void kernel_launch(void* const* d_in, const int* in_sizes, int n_in,
                              void* d_out, int out_size, void* d_ws, size_t ws_size,
                              hipStream_t stream) {
    const float* img = (const float*)d_in[0];  // (1,256,64,64,25) f32
    const float* W   = (const float*)d_in[1];  // (256,25) f32
    float* out       = (float*)d_out;          // (1,256,64,64) f32

    const int grid = out_size / (OPW * WAVES); // 1,048,576 / 256 = 4096
    medsam_compress_kernel<<<grid, BLOCK, 0, stream>>>(img, W, out);
}